// Round 1
// baseline (2122.713 us; speedup 1.0000x reference)
//
#include <hip/hip_runtime.h>

#define BATCH 32
#define HH 1024
#define WW 1024
#define NPIX (HH * WW)
#define NEROS 10

__device__ __forceinline__ float4 ld4(const float* p) {
    return *reinterpret_cast<const float4*>(p);
}

template <bool FIRST>
__device__ __forceinline__ float4 loadq(const float* __restrict__ pred,
                                        const float* __restrict__ tgt,
                                        const float* __restrict__ in, size_t idx) {
    if (FIRST) {
        float4 p = ld4(pred + idx), t = ld4(tgt + idx);
        float4 r;
        r.x = (p.x - t.x) * (p.x - t.x);
        r.y = (p.y - t.y) * (p.y - t.y);
        r.z = (p.z - t.z) * (p.z - t.z);
        r.w = (p.w - t.w) * (p.w - t.w);
        return r;
    } else {
        return ld4(in + idx);
    }
}

template <bool FIRST>
__device__ __forceinline__ float loads(const float* __restrict__ pred,
                                       const float* __restrict__ tgt,
                                       const float* __restrict__ in, size_t idx) {
    if (FIRST) {
        float d = pred[idx] - tgt[idx];
        return d * d;
    } else {
        return in[idx];
    }
}

// One block = one image row (1024 px), 256 threads x 4 px (float4).
// dil = conv(prev_er_normalized) done as (conv(raw) - c*K)/ptp  (affine fusion).
// er  = max(dil - 0.5, 0); write raw er; reduce per-sample min/max/sum.
template <bool FIRST>
__global__ __launch_bounds__(256) void conv_er_kernel(
    const float* __restrict__ pred, const float* __restrict__ tgt,
    const float* __restrict__ in, float* __restrict__ out,
    const unsigned* __restrict__ pmin, const unsigned* __restrict__ pmax,
    unsigned* __restrict__ omin, unsigned* __restrict__ omax,
    double* __restrict__ osum) {
    // XCD-aware swizzle (gridDim.x = 32768, divisible by 8 -> bijective)
    int blk = blockIdx.x;
    blk = (blk & 7) * (int)(gridDim.x >> 3) + (blk >> 3);

    const int s = blk >> 10;       // sample
    const int y = blk & 1023;      // row
    const int tid = threadIdx.x;
    const int x0 = tid << 2;
    const size_t base = (size_t)s * NPIX + (size_t)y * WW;

    float a = 1.f, cc = 0.f;
    if (!FIRST) {
        float mn = __uint_as_float(pmin[s]);
        float mx = __uint_as_float(pmax[s]);
        float ptp = mx - mn;
        if (ptp > 0.f) { a = 1.f / ptp; cc = mn; }
    }

    float4 ctr = loadq<FIRST>(pred, tgt, in, base + x0);
    float4 up = (y > 0) ? loadq<FIRST>(pred, tgt, in, base - WW + x0)
                        : make_float4(0.f, 0.f, 0.f, 0.f);
    float4 dn = (y < HH - 1) ? loadq<FIRST>(pred, tgt, in, base + WW + x0)
                             : make_float4(0.f, 0.f, 0.f, 0.f);
    float lf = (x0 > 0) ? loads<FIRST>(pred, tgt, in, base + x0 - 1) : 0.f;
    float rt = (x0 + 4 < WW) ? loads<FIRST>(pred, tgt, in, base + x0 + 4) : 0.f;

    float cv[4] = {ctr.x, ctr.y, ctr.z, ctr.w};
    float uv[4] = {up.x, up.y, up.z, up.w};
    float dv[4] = {dn.x, dn.y, dn.z, dn.w};
    float lv[4] = {lf, ctr.x, ctr.y, ctr.z};
    float rv[4] = {ctr.y, ctr.z, ctr.w, rt};

    const float vert = 1.f + (y > 0 ? 1.f : 0.f) + (y < HH - 1 ? 1.f : 0.f);

    float lmin = 3.4e38f, lmax = 0.f, lsum = 0.f;
    float o[4];
#pragma unroll
    for (int j = 0; j < 4; ++j) {
        float convsum = 0.2f * (cv[j] + uv[j] + dv[j] + lv[j] + rv[j]);
        float dil;
        if (FIRST) {
            dil = convsum;
        } else {
            float hasL = (x0 + j) > 0 ? 1.f : 0.f;
            float hasR = (x0 + j) < WW - 1 ? 1.f : 0.f;
            float kf = 0.2f * (vert + hasL + hasR);
            dil = (convsum - cc * kf) * a;
        }
        float er = fmaxf(dil - 0.5f, 0.f);
        o[j] = er;
        lmin = fminf(lmin, er);
        lmax = fmaxf(lmax, er);
        lsum += er;
    }
    *reinterpret_cast<float4*>(out + base + x0) =
        make_float4(o[0], o[1], o[2], o[3]);

    // wave reduction (64 lanes)
#pragma unroll
    for (int off = 32; off > 0; off >>= 1) {
        lmin = fminf(lmin, __shfl_down(lmin, off));
        lmax = fmaxf(lmax, __shfl_down(lmax, off));
        lsum += __shfl_down(lsum, off);
    }
    __shared__ float smn[4], smx[4], ssm[4];
    const int wid = tid >> 6, lane = tid & 63;
    if (lane == 0) { smn[wid] = lmin; smx[wid] = lmax; ssm[wid] = lsum; }
    __syncthreads();
    if (tid == 0) {
        float bmn = smn[0], bmx = smx[0], bsm = ssm[0];
#pragma unroll
        for (int w = 1; w < 4; ++w) {
            bmn = fminf(bmn, smn[w]);
            bmx = fmaxf(bmx, smx[w]);
            bsm += ssm[w];
        }
        // er >= 0, so float bit pattern is monotonic as unsigned
        atomicMin(&omin[s], __float_as_uint(bmn));
        atomicMax(&omax[s], __float_as_uint(bmx));
        atomicAdd(&osum[s], (double)bsm);
    }
}

__global__ void init_kernel(unsigned* __restrict__ minb,
                            unsigned* __restrict__ maxb,
                            double* __restrict__ sums) {
    int i = blockIdx.x * blockDim.x + threadIdx.x;
    if (i < NEROS * BATCH) {
        minb[i] = 0x7f800000u;  // +inf
        maxb[i] = 0u;
        sums[i] = 0.0;
    }
}

__global__ void final_kernel(const unsigned* __restrict__ minb,
                             const unsigned* __restrict__ maxb,
                             const double* __restrict__ sums,
                             float* __restrict__ out) {
    int s = threadIdx.x;  // 64 threads, s<32 active
    double tot = 0.0;
    if (s < BATCH) {
        for (int k = 0; k < NEROS; ++k) {
            float mn = __uint_as_float(minb[k * BATCH + s]);
            float mx = __uint_as_float(maxb[k * BATCH + s]);
            double sm = sums[k * BATCH + s];
            float ptp = mx - mn;
            double v;
            if (ptp > 0.f)
                v = (sm - (double)NPIX * (double)mn) / (double)ptp;
            else
                v = sm;
            double w = (double)((k + 1) * (k + 1));
            tot += w * v;
        }
    }
#pragma unroll
    for (int off = 32; off > 0; off >>= 1) tot += __shfl_down(tot, off);
    if (s == 0) out[0] = (float)(tot / ((double)BATCH * (double)NPIX));
}

extern "C" void kernel_launch(void* const* d_in, const int* in_sizes, int n_in,
                              void* d_out, int out_size, void* d_ws,
                              size_t ws_size, hipStream_t stream) {
    const float* pred = (const float*)d_in[0];
    const float* tgt = (const float*)d_in[1];
    float* out = (float*)d_out;

    float* buf0 = (float*)d_ws;
    float* buf1 = buf0 + (size_t)BATCH * NPIX;
    unsigned* minb = (unsigned*)(buf1 + (size_t)BATCH * NPIX);
    unsigned* maxb = minb + NEROS * BATCH;
    double* sums = (double*)(maxb + NEROS * BATCH);

    init_kernel<<<2, 256, 0, stream>>>(minb, maxb, sums);

    dim3 grid(BATCH * HH), block(256);
    conv_er_kernel<true><<<grid, block, 0, stream>>>(
        pred, tgt, nullptr, buf0, nullptr, nullptr, minb, maxb, sums);

    float* bufs[2] = {buf0, buf1};
    for (int k = 1; k < NEROS; ++k) {
        const float* src = bufs[(k - 1) & 1];
        float* dst = bufs[k & 1];
        conv_er_kernel<false><<<grid, block, 0, stream>>>(
            nullptr, nullptr, src, dst, minb + (size_t)(k - 1) * BATCH,
            maxb + (size_t)(k - 1) * BATCH, minb + (size_t)k * BATCH,
            maxb + (size_t)k * BATCH, sums + (size_t)k * BATCH);
    }

    final_kernel<<<1, 64, 0, stream>>>(minb, maxb, sums, out);
}

// Round 2
// 333.221 us; speedup vs baseline: 6.3703x; 6.3703x over previous
//
#include <hip/hip_runtime.h>

#define BATCH 32
#define HH 1024
#define WW 1024
#define NPIX (HH * WW)
#define NEROS 10
#define RPB 16                 // rows per tile/block
#define TPS 64                 // tiles per sample
#define NTILES (BATCH * TPS)   // 2048

__device__ __forceinline__ float4 ld4f(const float* p) {
    return *reinterpret_cast<const float4*>(p);
}

// One block = one 16-row tile. Thread t owns 4 px (x0=4t) across all 16 rows.
// Chunk = 16 rows x 64 px (16 chunks per tile). F masks: bit c set = chunk c
// has a nonzero value. Z masks: bit c set = chunk c of this buffer holds real
// zeros. Invariant after each iteration: F=0  ==>  buffer content is zeros.
template <bool FIRST>
__global__ __launch_bounds__(256) void conv_er_kernel(
    const float* __restrict__ pred, const float* __restrict__ tgt,
    const float* __restrict__ in, float* __restrict__ out,
    const unsigned* __restrict__ Fprev, unsigned* __restrict__ Fout,
    unsigned* __restrict__ Z,
    const unsigned* __restrict__ pmin, const unsigned* __restrict__ pmax,
    unsigned* __restrict__ omin, unsigned* __restrict__ omax,
    double* __restrict__ osum) {
    int blk = blockIdx.x;
    blk = (blk & 7) * (int)(gridDim.x >> 3) + (blk >> 3);  // XCD swizzle (2048%8==0)
    const int s = blk >> 6;
    const int ty = blk & (TPS - 1);
    const int ry = ty << 4;
    const int tid = threadIdx.x;
    const int x0 = tid << 2;
    const unsigned c = (unsigned)x0 >> 6;  // chunk id 0..15
    const size_t sbase = (size_t)s * (size_t)NPIX;

    unsigned m = 0xFFFFu;
    if (!FIRST) {
        m = Fprev[blk];
        if (ty > 0) m |= Fprev[blk - 1];
        if (ty < TPS - 1) m |= Fprev[blk + 1];
    }

    // Whole-tile skip: all inputs in reach are zero -> output tile is exactly 0.
    if (!FIRST && m == 0u) {
        const unsigned zw = Z[blk];
        if (!((zw >> c) & 1u)) {  // lazily establish real zeros once
            float* p = out + sbase + (size_t)ry * WW + x0;
            const float4 z4 = make_float4(0.f, 0.f, 0.f, 0.f);
#pragma unroll
            for (int r = 0; r < RPB; ++r) {
                *reinterpret_cast<float4*>(p) = z4;
                p += WW;
            }
        }
        if (tid == 0) {
            Fout[blk] = 0u;
            Z[blk] = 0xFFFFu;
            atomicMin(&omin[s], 0u);  // tile contributes min=0,max=0,sum=0
        }
        return;
    }

    const bool active = FIRST || ((((m << 1) >> c) & 7u) != 0u);  // bits c-1..c+1

    float a = 1.f, cc = 0.f;
    if (!FIRST) {
        const float mn = __uint_as_float(pmin[s]);
        const float mx = __uint_as_float(pmax[s]);
        const float ptp = mx - mn;
        if (ptp > 0.f) { a = 1.f / ptp; cc = mn; }
    }

    float lmin = 0.f, lmax = 0.f, lsum = 0.f;

    if (active) {
        lmin = 3.4e38f;
        auto loadrow = [&](int y) -> float4 {
            if (y < 0 || y >= HH) return make_float4(0.f, 0.f, 0.f, 0.f);
            const size_t idx = sbase + (size_t)y * WW + x0;
            if constexpr (FIRST) {
                const float4 p = ld4f(pred + idx), t = ld4f(tgt + idx);
                return make_float4((p.x - t.x) * (p.x - t.x),
                                   (p.y - t.y) * (p.y - t.y),
                                   (p.z - t.z) * (p.z - t.z),
                                   (p.w - t.w) * (p.w - t.w));
            } else {
                return ld4f(in + idx);
            }
        };
        auto loadsc = [&](int y, int x) -> float {
            const size_t idx = sbase + (size_t)y * WW + x;
            if constexpr (FIRST) {
                const float d = pred[idx] - tgt[idx];
                return d * d;
            } else {
                return in[idx];
            }
        };

        float4 up = loadrow(ry - 1);
        float4 ct = loadrow(ry);
#pragma unroll 4
        for (int r = 0; r < RPB; ++r) {
            const int y = ry + r;
            const float4 dn = loadrow(y + 1);
            const float lf = (x0 > 0) ? loadsc(y, x0 - 1) : 0.f;
            const float rt = (x0 + 4 < WW) ? loadsc(y, x0 + 4) : 0.f;

            const float cv[4] = {ct.x, ct.y, ct.z, ct.w};
            const float uv[4] = {up.x, up.y, up.z, up.w};
            const float dv[4] = {dn.x, dn.y, dn.z, dn.w};
            const float lv[4] = {lf, ct.x, ct.y, ct.z};
            const float rv[4] = {ct.y, ct.z, ct.w, rt};
            const float vert = 1.f + (y > 0 ? 1.f : 0.f) + (y < HH - 1 ? 1.f : 0.f);

            float o[4];
#pragma unroll
            for (int j = 0; j < 4; ++j) {
                const float convsum = 0.2f * (cv[j] + uv[j] + dv[j] + lv[j] + rv[j]);
                float dil;
                if constexpr (FIRST) {
                    dil = convsum;
                } else {
                    const float hasL = (x0 + j) > 0 ? 1.f : 0.f;
                    const float hasR = (x0 + j) < WW - 1 ? 1.f : 0.f;
                    const float kf = 0.2f * (vert + hasL + hasR);
                    dil = (convsum - cc * kf) * a;
                }
                const float er = fmaxf(dil - 0.5f, 0.f);
                o[j] = er;
                lmin = fminf(lmin, er);
                lmax = fmaxf(lmax, er);
                lsum += er;
            }
            *reinterpret_cast<float4*>(out + sbase + (size_t)y * WW + x0) =
                make_float4(o[0], o[1], o[2], o[3]);
            up = ct;
            ct = dn;
        }
    } else {
        const unsigned zw = Z[blk];
        if (!((zw >> c) & 1u)) {
            float* p = out + sbase + (size_t)ry * WW + x0;
            const float4 z4 = make_float4(0.f, 0.f, 0.f, 0.f);
#pragma unroll
            for (int r = 0; r < RPB; ++r) {
                *reinterpret_cast<float4*>(p) = z4;
                p += WW;
            }
        }
        // inactive lanes own exact-zero pixels: contribute (0,0,0)
    }

    // chunk-nonzero ballot (after reconvergence), then block reduce
    const unsigned long long bal = __ballot(lmax > 0.f);
#pragma unroll
    for (int off = 32; off > 0; off >>= 1) {
        lmin = fminf(lmin, __shfl_down(lmin, off));
        lmax = fmaxf(lmax, __shfl_down(lmax, off));
        lsum += __shfl_down(lsum, off);
    }

    __shared__ unsigned sF[4];
    __shared__ float smn[4], smx[4], ssm[4];
    const int w = tid >> 6, lane = tid & 63;
    if (lane == 0) {
        unsigned wn = 0;
#pragma unroll
        for (int j = 0; j < 4; ++j)
            if ((bal >> (16 * j)) & 0xFFFFull) wn |= 1u << (4 * w + j);
        sF[w] = wn;
        smn[w] = lmin;
        smx[w] = lmax;
        ssm[w] = lsum;
    }
    __syncthreads();
    if (tid == 0) {
        const unsigned fmask = sF[0] | sF[1] | sF[2] | sF[3];
        float bmn = smn[0], bmx = smx[0], bsm = ssm[0];
#pragma unroll
        for (int i = 1; i < 4; ++i) {
            bmn = fminf(bmn, smn[i]);
            bmx = fmaxf(bmx, smx[i]);
            bsm += ssm[i];
        }
        Fout[blk] = fmask;
        Z[blk] = (~fmask) & 0xFFFFu;
        atomicMin(&omin[s], __float_as_uint(bmn));
        if (bmx > 0.f) atomicMax(&omax[s], __float_as_uint(bmx));
        if (bsm > 0.f) atomicAdd(&osum[s], (double)bsm);
    }
}

__global__ void init_kernel(unsigned* __restrict__ minb,
                            unsigned* __restrict__ maxb,
                            double* __restrict__ sums,
                            unsigned* __restrict__ Z) {
    const int i = blockIdx.x * blockDim.x + threadIdx.x;
    if (i < NEROS * BATCH) {
        minb[i] = 0x7f800000u;  // +inf
        maxb[i] = 0u;
        sums[i] = 0.0;
    }
    if (i < 2 * NTILES) Z[i] = 0u;  // content unknown
}

__global__ void final_kernel(const unsigned* __restrict__ minb,
                             const unsigned* __restrict__ maxb,
                             const double* __restrict__ sums,
                             float* __restrict__ out) {
    const int s = threadIdx.x;
    double tot = 0.0;
    if (s < BATCH) {
        for (int k = 0; k < NEROS; ++k) {
            const float mn = __uint_as_float(minb[k * BATCH + s]);
            const float mx = __uint_as_float(maxb[k * BATCH + s]);
            const double sm = sums[k * BATCH + s];
            const float ptp = mx - mn;
            double v;
            if (ptp > 0.f)
                v = (sm - (double)NPIX * (double)mn) / (double)ptp;
            else
                v = sm;
            tot += (double)((k + 1) * (k + 1)) * v;
        }
    }
#pragma unroll
    for (int off = 32; off > 0; off >>= 1) tot += __shfl_down(tot, off);
    if (s == 0) out[0] = (float)(tot / ((double)BATCH * (double)NPIX));
}

extern "C" void kernel_launch(void* const* d_in, const int* in_sizes, int n_in,
                              void* d_out, int out_size, void* d_ws,
                              size_t ws_size, hipStream_t stream) {
    const float* pred = (const float*)d_in[0];
    const float* tgt = (const float*)d_in[1];
    float* out = (float*)d_out;

    float* buf0 = (float*)d_ws;
    float* buf1 = buf0 + (size_t)BATCH * NPIX;
    unsigned* minb = (unsigned*)(buf1 + (size_t)BATCH * NPIX);
    unsigned* maxb = minb + NEROS * BATCH;
    double* sums = (double*)(maxb + NEROS * BATCH);
    unsigned* F = (unsigned*)(sums + NEROS * BATCH);
    unsigned* Z = F + (size_t)NEROS * NTILES;

    init_kernel<<<16, 256, 0, stream>>>(minb, maxb, sums, Z);

    dim3 grid(NTILES), block(256);
    conv_er_kernel<true><<<grid, block, 0, stream>>>(
        pred, tgt, nullptr, buf0, nullptr, F, Z, nullptr, nullptr, minb, maxb,
        sums);

    float* bufs[2] = {buf0, buf1};
    for (int k = 1; k < NEROS; ++k) {
        const float* src = bufs[(k - 1) & 1];
        float* dst = bufs[k & 1];
        conv_er_kernel<false><<<grid, block, 0, stream>>>(
            nullptr, nullptr, src, dst, F + (size_t)(k - 1) * NTILES,
            F + (size_t)k * NTILES, Z + (size_t)(k & 1) * NTILES,
            minb + (size_t)(k - 1) * BATCH, maxb + (size_t)(k - 1) * BATCH,
            minb + (size_t)k * BATCH, maxb + (size_t)k * BATCH,
            sums + (size_t)k * BATCH);
    }

    final_kernel<<<1, 64, 0, stream>>>(minb, maxb, sums, out);
}

// Round 3
// 219.453 us; speedup vs baseline: 9.6727x; 1.5184x over previous
//
#include <hip/hip_runtime.h>

#define BATCH 32
#define HH 1024
#define WW 1024
#define NPIX (HH * WW)
#define NEROS 10
#define RPB 16                 // rows per tile/block
#define TPS 64                 // tiles per sample
#define NTILES (BATCH * TPS)   // 2048
#define FWORDS 128             // flag words per sample: 1024 rows / 8

__device__ __forceinline__ float4 ld4f(const float* p) {
    return *reinterpret_cast<const float4*>(p);
}

// flag nibble for row y (4 bits, one per 256-px wave chunk); fw0..fw3 cover
// rows [ry-8, ry+24). y must be in [ry-1, ry+16].
__device__ __forceinline__ unsigned nibOf(unsigned fw0, unsigned fw1,
                                          unsigned fw2, unsigned fw3,
                                          int ry, int y) {
    const int r = y - ry;        // -1 .. 16
    const int sel = (r >> 3) + 1;  // 0..3 (arith shift: -1>>3 == -1)
    unsigned w = sel == 0 ? fw0 : (sel == 1 ? fw1 : (sel == 2 ? fw2 : fw3));
    return (w >> ((y & 7) * 4)) & 0xFu;
}

// One block = 16-row tile, 256 threads; wave w owns the 256-px column chunk
// wc==w of every row. Flag bit (per row, per chunk) = chunk has a nonzero.
// Rows whose flag is 0 are logically zero and their memory is NEVER read,
// so nothing is ever zero-filled. A wave writes its row segment only if the
// computed values contain a nonzero (ballot), and sets the flag bit.
template <bool FIRST>
__global__ __launch_bounds__(256) void conv_er_kernel(
    const float* __restrict__ pred, const float* __restrict__ tgt,
    const float* __restrict__ in, float* __restrict__ out,
    const unsigned* __restrict__ Fprev, unsigned* __restrict__ Fout,
    const unsigned* __restrict__ pmin, const unsigned* __restrict__ pmax,
    unsigned* __restrict__ omin, unsigned* __restrict__ omax,
    double* __restrict__ osum) {
    int blk = blockIdx.x;
    blk = (blk & 7) * (int)(gridDim.x >> 3) + (blk >> 3);  // XCD swizzle
    const int s = blk >> 6;
    const int ty = blk & (TPS - 1);
    const int ry = ty << 4;
    const int tid = threadIdx.x;
    const int lane = tid & 63;
    const int wc = tid >> 6;   // wave id == 256-px chunk column
    const int x0 = tid << 2;
    const size_t sbase = (size_t)s * (size_t)NPIX;

    unsigned fw0 = 0, fw1 = 0, fw2 = 0, fw3 = 0;
    if (!FIRST) {
        const int y8 = ry >> 3;
        const unsigned* Fs = Fprev + s * FWORDS;
        fw0 = (y8 > 0) ? Fs[y8 - 1] : 0u;
        fw1 = Fs[y8];
        fw2 = Fs[y8 + 1];
        fw3 = (y8 + 2 < FWORDS) ? Fs[y8 + 2] : 0u;
        if ((fw0 | fw1 | fw2 | fw3) == 0u) {  // nothing in reach: tile is 0
            if (tid == 0) {
                Fout[s * FWORDS + y8] = 0u;
                Fout[s * FWORDS + y8 + 1] = 0u;
                atomicMin(&omin[s], 0u);
            }
            return;
        }
    }

    float a = 1.f, cc = 0.f;
    if (!FIRST) {
        const float mn = __uint_as_float(pmin[s]);
        const float mx = __uint_as_float(pmax[s]);
        const float ptp = mx - mn;
        if (ptp > 0.f) { a = 1.f / ptp; cc = mn; }
    }

    // load row y: value quad + left/right horizontal taps (via shfl)
    auto loadRow = [&](int y, unsigned nib, float4& v, float& lf, float& rt) {
        v = make_float4(0.f, 0.f, 0.f, 0.f);
        lf = 0.f;
        rt = 0.f;
        if (y < 0 || y >= HH) return;
        const size_t idx = sbase + (size_t)y * WW + x0;
        if constexpr (FIRST) {
            const float4 p = ld4f(pred + idx), t = ld4f(tgt + idx);
            v = make_float4((p.x - t.x) * (p.x - t.x),
                            (p.y - t.y) * (p.y - t.y),
                            (p.z - t.z) * (p.z - t.z),
                            (p.w - t.w) * (p.w - t.w));
        } else {
            if ((nib >> wc) & 1u) v = ld4f(in + idx);
        }
        lf = __shfl_up(v.w, 1);
        rt = __shfl_down(v.x, 1);
        if (lane == 0) {
            if (x0 == 0) {
                lf = 0.f;
            } else if constexpr (FIRST) {
                const float d = pred[idx - 1] - tgt[idx - 1];
                lf = d * d;
            } else {
                lf = ((nib >> (wc - 1)) & 1u) ? in[idx - 1] : 0.f;
            }
        }
        if (lane == 63) {
            if (x0 + 4 >= WW) {
                rt = 0.f;
            } else if constexpr (FIRST) {
                const float d = pred[idx + 4] - tgt[idx + 4];
                rt = d * d;
            } else {
                rt = ((nib >> (wc + 1)) & 1u) ? in[idx + 4] : 0.f;
            }
        }
    };

    unsigned nU = FIRST ? 0u : nibOf(fw0, fw1, fw2, fw3, ry, ry - 1);
    unsigned nC = FIRST ? 0u : nibOf(fw0, fw1, fw2, fw3, ry, ry);
    float4 vU, vC, vD;
    float lfU, rtU, lfC, rtC, lfD, rtD;
    loadRow(ry - 1, nU, vU, lfU, rtU);
    loadRow(ry, nC, vC, lfC, rtC);

    float lmin = 3.4e38f, lmax = 0.f, lsum = 0.f;
    unsigned rowbits = 0u;

#pragma unroll 4
    for (int r = 0; r < RPB; ++r) {
        const int y = ry + r;
        const unsigned nD = FIRST ? 0u : nibOf(fw0, fw1, fw2, fw3, ry, y + 1);
        loadRow(y + 1, nD, vD, lfD, rtD);

        const bool act = FIRST || (((((nU | nC | nD) << 1)) >> wc) & 7u);
        if (act) {
            const float cv[4] = {vC.x, vC.y, vC.z, vC.w};
            const float uv[4] = {vU.x, vU.y, vU.z, vU.w};
            const float dv[4] = {vD.x, vD.y, vD.z, vD.w};
            const float lv[4] = {lfC, vC.x, vC.y, vC.z};
            const float rv[4] = {vC.y, vC.z, vC.w, rtC};
            const float vert =
                1.f + (y > 0 ? 1.f : 0.f) + (y < HH - 1 ? 1.f : 0.f);

            float o[4];
            bool nz = false;
#pragma unroll
            for (int j = 0; j < 4; ++j) {
                const float convsum =
                    0.2f * (cv[j] + uv[j] + dv[j] + lv[j] + rv[j]);
                float dil;
                if constexpr (FIRST) {
                    dil = convsum;
                } else {
                    const float hasL = (x0 + j) > 0 ? 1.f : 0.f;
                    const float hasR = (x0 + j) < WW - 1 ? 1.f : 0.f;
                    const float kf = 0.2f * (vert + hasL + hasR);
                    dil = (convsum - cc * kf) * a;
                }
                const float er = fmaxf(dil - 0.5f, 0.f);
                o[j] = er;
                lmin = fminf(lmin, er);
                lmax = fmaxf(lmax, er);
                lsum += er;
                nz = nz || (er > 0.f);
            }
            const unsigned long long bal = __ballot(nz);
            if (bal != 0ull) {  // wave-uniform: write the 256-px row segment
                *reinterpret_cast<float4*>(out + sbase + (size_t)y * WW + x0) =
                    make_float4(o[0], o[1], o[2], o[3]);
                rowbits |= 1u << r;
            }
        } else {
            lmin = fminf(lmin, 0.f);  // this row segment is exactly zero
        }
        vU = vC; lfC = lfD; rtC = rtD; vC = vD; nU = nC; nC = nD;
    }

    // wave reduce
#pragma unroll
    for (int off = 32; off > 0; off >>= 1) {
        lmin = fminf(lmin, __shfl_down(lmin, off));
        lmax = fmaxf(lmax, __shfl_down(lmax, off));
        lsum += __shfl_down(lsum, off);
    }
    __shared__ float smn[4], smx[4], ssm[4];
    __shared__ unsigned sfb[4];
    if (lane == 0) {
        smn[wc] = lmin;
        smx[wc] = lmax;
        ssm[wc] = lsum;
        sfb[wc] = rowbits;
    }
    __syncthreads();
    if (tid == 0) {
        const unsigned rb0 = sfb[0], rb1 = sfb[1], rb2 = sfb[2], rb3 = sfb[3];
        unsigned w0 = 0u, w1 = 0u;
#pragma unroll
        for (int r = 0; r < 8; ++r) {
            const unsigned nib = ((rb0 >> r) & 1u) | (((rb1 >> r) & 1u) << 1) |
                                 (((rb2 >> r) & 1u) << 2) |
                                 (((rb3 >> r) & 1u) << 3);
            w0 |= nib << (r * 4);
        }
#pragma unroll
        for (int r = 8; r < 16; ++r) {
            const unsigned nib = ((rb0 >> r) & 1u) | (((rb1 >> r) & 1u) << 1) |
                                 (((rb2 >> r) & 1u) << 2) |
                                 (((rb3 >> r) & 1u) << 3);
            w1 |= nib << ((r - 8) * 4);
        }
        Fout[s * FWORDS + (ry >> 3)] = w0;
        Fout[s * FWORDS + (ry >> 3) + 1] = w1;

        float bmn = smn[0], bmx = smx[0], bsm = ssm[0];
#pragma unroll
        for (int i = 1; i < 4; ++i) {
            bmn = fminf(bmn, smn[i]);
            bmx = fmaxf(bmx, smx[i]);
            bsm += ssm[i];
        }
        atomicMin(&omin[s], __float_as_uint(bmn));
        if (bmx > 0.f) atomicMax(&omax[s], __float_as_uint(bmx));
        if (bsm > 0.f) atomicAdd(&osum[s], (double)bsm);
    }
}

__global__ void init_kernel(unsigned* __restrict__ minb,
                            unsigned* __restrict__ maxb,
                            double* __restrict__ sums) {
    const int i = blockIdx.x * blockDim.x + threadIdx.x;
    if (i < NEROS * BATCH) {
        minb[i] = 0x7f800000u;  // +inf
        maxb[i] = 0u;
        sums[i] = 0.0;
    }
}

__global__ void final_kernel(const unsigned* __restrict__ minb,
                             const unsigned* __restrict__ maxb,
                             const double* __restrict__ sums,
                             float* __restrict__ out) {
    const int s = threadIdx.x;
    double tot = 0.0;
    if (s < BATCH) {
        for (int k = 0; k < NEROS; ++k) {
            const float mn = __uint_as_float(minb[k * BATCH + s]);
            const float mx = __uint_as_float(maxb[k * BATCH + s]);
            const double sm = sums[k * BATCH + s];
            const float ptp = mx - mn;
            double v;
            if (ptp > 0.f)
                v = (sm - (double)NPIX * (double)mn) / (double)ptp;
            else
                v = sm;
            tot += (double)((k + 1) * (k + 1)) * v;
        }
    }
#pragma unroll
    for (int off = 32; off > 0; off >>= 1) tot += __shfl_down(tot, off);
    if (s == 0) out[0] = (float)(tot / ((double)BATCH * (double)NPIX));
}

extern "C" void kernel_launch(void* const* d_in, const int* in_sizes, int n_in,
                              void* d_out, int out_size, void* d_ws,
                              size_t ws_size, hipStream_t stream) {
    const float* pred = (const float*)d_in[0];
    const float* tgt = (const float*)d_in[1];
    float* out = (float*)d_out;

    float* buf0 = (float*)d_ws;
    float* buf1 = buf0 + (size_t)BATCH * NPIX;
    unsigned* minb = (unsigned*)(buf1 + (size_t)BATCH * NPIX);
    unsigned* maxb = minb + NEROS * BATCH;
    double* sums = (double*)(maxb + NEROS * BATCH);
    unsigned* F = (unsigned*)(sums + NEROS * BATCH);

    init_kernel<<<2, 256, 0, stream>>>(minb, maxb, sums);

    dim3 grid(NTILES), block(256);
    conv_er_kernel<true><<<grid, block, 0, stream>>>(
        pred, tgt, nullptr, buf0, nullptr, F, nullptr, nullptr, minb, maxb,
        sums);

    float* bufs[2] = {buf0, buf1};
    for (int k = 1; k < NEROS; ++k) {
        const float* src = bufs[(k - 1) & 1];
        float* dst = bufs[k & 1];
        conv_er_kernel<false><<<grid, block, 0, stream>>>(
            nullptr, nullptr, src, dst, F + (size_t)(k - 1) * BATCH * FWORDS,
            F + (size_t)k * BATCH * FWORDS, minb + (size_t)(k - 1) * BATCH,
            maxb + (size_t)(k - 1) * BATCH, minb + (size_t)k * BATCH,
            maxb + (size_t)k * BATCH, sums + (size_t)k * BATCH);
    }

    final_kernel<<<1, 64, 0, stream>>>(minb, maxb, sums, out);
}

// Round 4
// 147.304 us; speedup vs baseline: 14.4104x; 1.4898x over previous
//
#include <hip/hip_runtime.h>

#define BATCH 32
#define HH 1024
#define WW 1024
#define NPIX (HH * WW)
#define NEROS 10
#define TPS 64                // 16-row tiles per sample
#define NTILES (BATCH * TPS)  // 2048

__device__ __forceinline__ float4 ld4f(const float* p) {
    return *reinterpret_cast<const float4*>(p);
}

// Block = one 16-row tile, 4 waves; wave w owns rows [ry+4w, ry+4w+4).
// Lane owns 16 consecutive px (full row per wave => horizontal taps are
// register-internal except lane seams: 2 shfls/row, image border = 0).
// Flags: 1 bit per row (ushort per tile): bit set = row has a nonzero.
// Unflagged rows are exact zeros and their memory is never read.
template <bool FIRST>
__global__ __launch_bounds__(256, 4) void conv_er_kernel(
    const float* __restrict__ pred, const float* __restrict__ tgt,
    const float* __restrict__ in, float* __restrict__ out,
    const unsigned short* __restrict__ Fprev, unsigned short* __restrict__ Fout,
    const unsigned* __restrict__ cntPrev, unsigned* __restrict__ cntOut,
    const unsigned* __restrict__ pmin, const unsigned* __restrict__ pmax,
    unsigned* __restrict__ omin, unsigned* __restrict__ omax,
    double* __restrict__ osum) {
    if (!FIRST && *cntPrev == 0u) return;  // field died: absorbing state

    int blk = blockIdx.x;
    blk = (blk & 7) * (NTILES >> 3) + (blk >> 3);  // XCD swizzle (2048%8==0)
    const int s = blk >> 6, ty = blk & 63, ry = ty << 4;
    const int tid = threadIdx.x, lane = tid & 63, w = tid >> 6;
    const int xb = lane << 4;
    const size_t sbase = (size_t)s * NPIX;

    // M: bit (i+1) = row ry+i flagged, i in [-1,16]
    unsigned M = 0x3FFFFu;
    if (!FIRST) {
        const unsigned short* Fs = Fprev + s * TPS;
        M = ((unsigned)Fs[ty]) << 1;
        if (ty > 0) M |= (Fs[ty - 1] >> 15) & 1u;
        if (ty < TPS - 1) M |= ((unsigned)(Fs[ty + 1] & 1u)) << 17;
        if (M == 0u) {  // nothing in reach: tile output exactly zero
            if (tid == 0) {
                Fout[s * TPS + ty] = 0;
                atomicMin(&omin[s], 0u);
            }
            return;
        }
    }

    float a = 1.f, cc = 0.f;
    if (!FIRST) {
        const float mn = __uint_as_float(pmin[s]);
        const float mx = __uint_as_float(pmax[s]);
        const float ptp = mx - mn;
        if (ptp > 0.f) { a = 1.f / ptp; cc = mn; }
    }

    const int r0 = w << 2;  // wave's first output row within tile

    float A[16], B[16], C[16], O[16];

    auto loadRow = [&](int y, float* V) {
        bool ok = (y >= 0 && y < HH);
        if (!FIRST) ok = ok && (((M >> (y - ry + 1)) & 1u) != 0u);
        if (!ok) {
#pragma unroll
            for (int j = 0; j < 16; ++j) V[j] = 0.f;
            return;
        }
        const size_t idx = sbase + (size_t)y * WW + xb;
#pragma unroll
        for (int q = 0; q < 4; ++q) {
            if constexpr (FIRST) {
                const float4 p = ld4f(pred + idx + 4 * q);
                const float4 t = ld4f(tgt + idx + 4 * q);
                V[4 * q + 0] = (p.x - t.x) * (p.x - t.x);
                V[4 * q + 1] = (p.y - t.y) * (p.y - t.y);
                V[4 * q + 2] = (p.z - t.z) * (p.z - t.z);
                V[4 * q + 3] = (p.w - t.w) * (p.w - t.w);
            } else {
                const float4 v = ld4f(in + idx + 4 * q);
                V[4 * q + 0] = v.x;
                V[4 * q + 1] = v.y;
                V[4 * q + 2] = v.z;
                V[4 * q + 3] = v.w;
            }
        }
    };

    loadRow(ry + r0 - 1, A);
    loadRow(ry + r0, B);

    float lmin = 3.4e38f, lmax = 0.f, lsum = 0.f;
    unsigned rowbits = 0u;

#pragma unroll
    for (int r = 0; r < 4; ++r) {
        const int y = ry + r0 + r;
        loadRow(y + 1, C);
        const bool act = FIRST || (((M >> (r0 + r)) & 7u) != 0u);
        if (act) {
            float lfe = __shfl_up(B[15], 1);
            if (lane == 0) lfe = 0.f;
            float rte = __shfl_down(B[0], 1);
            if (lane == 63) rte = 0.f;
            const float vert =
                1.f + (y > 0 ? 1.f : 0.f) + (y < HH - 1 ? 1.f : 0.f);
            bool nz = false;
#pragma unroll
            for (int j = 0; j < 16; ++j) {
                const float lf = (j == 0) ? lfe : B[j - 1];
                const float rt = (j == 15) ? rte : B[j + 1];
                const float conv = 0.2f * (A[j] + C[j] + B[j] + lf + rt);
                float dil;
                if constexpr (FIRST) {
                    dil = conv;
                } else {
                    const int x = xb + j;
                    const float kf =
                        0.2f * (vert + (x > 0 ? 1.f : 0.f) +
                                (x < WW - 1 ? 1.f : 0.f));
                    dil = (conv - cc * kf) * a;
                }
                const float er = fmaxf(dil - 0.5f, 0.f);
                O[j] = er;
                lmin = fminf(lmin, er);
                lmax = fmaxf(lmax, er);
                lsum += er;
                nz = nz || (er > 0.f);
            }
            if (__ballot(nz) != 0ull) {  // wave-uniform: write whole row
                const size_t oidx = sbase + (size_t)y * WW + xb;
#pragma unroll
                for (int q = 0; q < 4; ++q)
                    *reinterpret_cast<float4*>(out + oidx + 4 * q) =
                        make_float4(O[4 * q], O[4 * q + 1], O[4 * q + 2],
                                    O[4 * q + 3]);
                rowbits |= 1u << (r0 + r);
            }
        } else {
            lmin = fminf(lmin, 0.f);  // row is exactly zero
        }
#pragma unroll
        for (int j = 0; j < 16; ++j) {
            A[j] = B[j];
            B[j] = C[j];
        }
    }

    // wave reduce, then block reduce via LDS
#pragma unroll
    for (int off = 32; off > 0; off >>= 1) {
        lmin = fminf(lmin, __shfl_down(lmin, off));
        lmax = fmaxf(lmax, __shfl_down(lmax, off));
        lsum += __shfl_down(lsum, off);
    }
    __shared__ float smn[4], smx[4], ssm[4];
    __shared__ unsigned sfb[4];
    if (lane == 0) {
        smn[w] = lmin;
        smx[w] = lmax;
        ssm[w] = lsum;
        sfb[w] = rowbits;
    }
    __syncthreads();
    if (tid == 0) {
        const unsigned fmask = sfb[0] | sfb[1] | sfb[2] | sfb[3];
        float bmn = smn[0], bmx = smx[0], bsm = ssm[0];
#pragma unroll
        for (int i = 1; i < 4; ++i) {
            bmn = fminf(bmn, smn[i]);
            bmx = fmaxf(bmx, smx[i]);
            bsm += ssm[i];
        }
        Fout[s * TPS + ty] = (unsigned short)fmask;
        if (fmask) atomicAdd(cntOut, 1u);
        atomicMin(&omin[s], __float_as_uint(bmn));
        if (bmx > 0.f) atomicMax(&omax[s], __float_as_uint(bmx));
        if (bsm > 0.f) atomicAdd(&osum[s], (double)bsm);
    }
}

__global__ void init_kernel(unsigned* __restrict__ minb,
                            unsigned* __restrict__ maxb,
                            double* __restrict__ sums,
                            unsigned* __restrict__ cnt) {
    const int i = blockIdx.x * blockDim.x + threadIdx.x;
    if (i < NEROS * BATCH) {
        minb[i] = 0x7f800000u;  // +inf
        maxb[i] = 0u;
        sums[i] = 0.0;
    }
    if (i < NEROS) cnt[i] = 0u;
}

__global__ void final_kernel(const unsigned* __restrict__ minb,
                             const unsigned* __restrict__ maxb,
                             const double* __restrict__ sums,
                             float* __restrict__ out) {
    const int s = threadIdx.x;
    double tot = 0.0;
    if (s < BATCH) {
        for (int k = 0; k < NEROS; ++k) {
            const float mn = __uint_as_float(minb[k * BATCH + s]);
            const float mx = __uint_as_float(maxb[k * BATCH + s]);
            const double sm = sums[k * BATCH + s];
            const float ptp = mx - mn;
            double v;
            if (ptp > 0.f)
                v = (sm - (double)NPIX * (double)mn) / (double)ptp;
            else
                v = sm;
            tot += (double)((k + 1) * (k + 1)) * v;
        }
    }
#pragma unroll
    for (int off = 32; off > 0; off >>= 1) tot += __shfl_down(tot, off);
    if (s == 0) out[0] = (float)(tot / ((double)BATCH * (double)NPIX));
}

extern "C" void kernel_launch(void* const* d_in, const int* in_sizes, int n_in,
                              void* d_out, int out_size, void* d_ws,
                              size_t ws_size, hipStream_t stream) {
    const float* pred = (const float*)d_in[0];
    const float* tgt = (const float*)d_in[1];
    float* out = (float*)d_out;

    float* buf0 = (float*)d_ws;
    float* buf1 = buf0 + (size_t)BATCH * NPIX;
    unsigned* minb = (unsigned*)(buf1 + (size_t)BATCH * NPIX);
    unsigned* maxb = minb + NEROS * BATCH;
    double* sums = (double*)(maxb + NEROS * BATCH);
    unsigned short* F = (unsigned short*)(sums + NEROS * BATCH);
    unsigned* cnt = (unsigned*)(F + (size_t)NEROS * NTILES);

    init_kernel<<<2, 256, 0, stream>>>(minb, maxb, sums, cnt);

    dim3 grid(NTILES), block(256);
    conv_er_kernel<true><<<grid, block, 0, stream>>>(
        pred, tgt, nullptr, buf0, nullptr, F, nullptr, &cnt[0], nullptr,
        nullptr, minb, maxb, sums);

    float* bufs[2] = {buf0, buf1};
    for (int k = 1; k < NEROS; ++k) {
        const float* src = bufs[(k - 1) & 1];
        float* dst = bufs[k & 1];
        conv_er_kernel<false><<<grid, block, 0, stream>>>(
            nullptr, nullptr, src, dst, F + (size_t)(k - 1) * NTILES,
            F + (size_t)k * NTILES, &cnt[k - 1], &cnt[k],
            minb + (size_t)(k - 1) * BATCH, maxb + (size_t)(k - 1) * BATCH,
            minb + (size_t)k * BATCH, maxb + (size_t)k * BATCH,
            sums + (size_t)k * BATCH);
    }

    final_kernel<<<1, 64, 0, stream>>>(minb, maxb, sums, out);
}

// Round 5
// 131.320 us; speedup vs baseline: 16.1644x; 1.1217x over previous
//
#include <hip/hip_runtime.h>

#define BATCH 32
#define HH 1024
#define WW 1024
#define NPIX (HH * WW)
#define NEROS 10
#define TPS 64                // 16-row tiles per sample
#define NTILES (BATCH * TPS)  // 2048
#define FWPS 32               // flag words per sample: uint per 32 rows

__device__ __forceinline__ float4 ld4f(const float* p) {
    return *reinterpret_cast<const float4*>(p);
}

// ---------------- iteration 0: LDS-staged fused bound+conv ----------------
// Block = 16-row tile, 512 threads (8 waves). Stage rows [ry-1, ry+17) of
// bound=(pred-tgt)^2 into LDS with one flat burst of 18 independent coalesced
// dwordx4 loads per thread (deep MLP), then each wave computes 2 rows from
// LDS. Row written to global only if it contains a nonzero (flag bit set).
__global__ __launch_bounds__(512, 4) void conv0_kernel(
    const float* __restrict__ pred, const float* __restrict__ tgt,
    float* __restrict__ out, unsigned* __restrict__ Fout,
    unsigned* __restrict__ cntOut, unsigned* __restrict__ omin,
    unsigned* __restrict__ omax, double* __restrict__ osum) {
    int blk = blockIdx.x;
    blk = (blk & 7) * (NTILES >> 3) + (blk >> 3);  // XCD swizzle
    const int s = blk >> 6, ty = blk & 63, ry = ty << 4;
    const int tid = threadIdx.x, lane = tid & 63, w = tid >> 6;  // w: 0..7
    const size_t sbase = (size_t)s * NPIX;

    __shared__ float sb[18 * 1024];  // 72 KB

    // ---- stage: 18 rows x 1024 px = 4608 float4 slots, 9 per thread ----
    float4 pv[9], tv[9];
#pragma unroll
    for (int i = 0; i < 9; ++i) {
        const int slot = tid + 512 * i;
        const int y = ry - 1 + (slot >> 8);
        if (y >= 0 && y < HH) {
            const size_t idx = sbase + (size_t)y * WW + ((slot & 255) << 2);
            pv[i] = ld4f(pred + idx);
            tv[i] = ld4f(tgt + idx);
        } else {
            pv[i] = make_float4(0.f, 0.f, 0.f, 0.f);
            tv[i] = make_float4(0.f, 0.f, 0.f, 0.f);
        }
    }
#pragma unroll
    for (int i = 0; i < 9; ++i) {
        const int slot = tid + 512 * i;
        float4 b;
        b.x = (pv[i].x - tv[i].x) * (pv[i].x - tv[i].x);
        b.y = (pv[i].y - tv[i].y) * (pv[i].y - tv[i].y);
        b.z = (pv[i].z - tv[i].z) * (pv[i].z - tv[i].z);
        b.w = (pv[i].w - tv[i].w) * (pv[i].w - tv[i].w);
        *reinterpret_cast<float4*>(
            &sb[(slot >> 8) * 1024 + ((slot & 255) << 2)]) = b;
    }
    __syncthreads();

    // ---- compute: wave w handles tile rows 2w, 2w+1 ----
    float lmin = 3.4e38f, lmax = 0.f, lsum = 0.f;
    unsigned rowbits = 0u;
#pragma unroll
    for (int rr = 0; rr < 2; ++rr) {
        const int yl = (w << 1) + rr;  // 0..15
        const int y = ry + yl;
        float O[16];
        bool nz = false;
#pragma unroll
        for (int q = 0; q < 4; ++q) {
            const int xw = (q << 8) + (lane << 2);
            const float4 U = *(const float4*)&sb[yl * 1024 + xw];
            const float4 Cc = *(const float4*)&sb[(yl + 1) * 1024 + xw];
            const float4 D = *(const float4*)&sb[(yl + 2) * 1024 + xw];
            float lf = __shfl_up(Cc.w, 1);
            if (lane == 0)
                lf = (q > 0) ? sb[(yl + 1) * 1024 + (q << 8) - 1] : 0.f;
            float rt = __shfl_down(Cc.x, 1);
            if (lane == 63)
                rt = (q < 3) ? sb[(yl + 1) * 1024 + (q << 8) + 256] : 0.f;
            const float cv[4] = {Cc.x, Cc.y, Cc.z, Cc.w};
            const float uv[4] = {U.x, U.y, U.z, U.w};
            const float dv[4] = {D.x, D.y, D.z, D.w};
            const float lvv[4] = {lf, Cc.x, Cc.y, Cc.z};
            const float rvv[4] = {Cc.y, Cc.z, Cc.w, rt};
#pragma unroll
            for (int j = 0; j < 4; ++j) {
                const float conv =
                    0.2f * (uv[j] + dv[j] + cv[j] + lvv[j] + rvv[j]);
                const float er = fmaxf(conv - 0.5f, 0.f);
                O[(q << 2) + j] = er;
                lmin = fminf(lmin, er);
                lmax = fmaxf(lmax, er);
                lsum += er;
                nz = nz || (er > 0.f);
            }
        }
        if (__ballot(nz) != 0ull) {  // wave-uniform: write whole row
            const size_t ob = sbase + (size_t)y * WW;
#pragma unroll
            for (int q = 0; q < 4; ++q)
                *reinterpret_cast<float4*>(out + ob + (q << 8) + (lane << 2)) =
                    make_float4(O[q << 2], O[(q << 2) + 1], O[(q << 2) + 2],
                                O[(q << 2) + 3]);
            rowbits |= 1u << yl;
        }
    }

    // ---- block reduce (8 waves) ----
#pragma unroll
    for (int off = 32; off > 0; off >>= 1) {
        lmin = fminf(lmin, __shfl_down(lmin, off));
        lmax = fmaxf(lmax, __shfl_down(lmax, off));
        lsum += __shfl_down(lsum, off);
    }
    __shared__ float smn[8], smx[8], ssm[8];
    __shared__ unsigned sfb[8];
    if (lane == 0) {
        smn[w] = lmin;
        smx[w] = lmax;
        ssm[w] = lsum;
        sfb[w] = rowbits;
    }
    __syncthreads();
    if (tid == 0) {
        unsigned fmask = 0u;
        float bmn = smn[0], bmx = smx[0], bsm = ssm[0];
        fmask = sfb[0];
#pragma unroll
        for (int i = 1; i < 8; ++i) {
            bmn = fminf(bmn, smn[i]);
            bmx = fmaxf(bmx, smx[i]);
            bsm += ssm[i];
            fmask |= sfb[i];
        }
        if (fmask) {
            atomicOr(&Fout[s * FWPS + (ty >> 1)], fmask << ((ty & 1) * 16));
            atomicAdd(cntOut, 1u);
        }
        atomicMin(&omin[s], __float_as_uint(bmn));
        if (bmx > 0.f) atomicMax(&omax[s], __float_as_uint(bmx));
        if (bsm > 0.f) atomicAdd(&osum[s], (double)bsm);
    }
}

// ---------------- iterations 1..9 (sparse tail) ----------------
// Block = 16-row tile, 4 waves; wave w owns rows [ry+4w, ry+4w+4); lane owns
// 16 px. Flag bit per row (uint per 32 rows): set = row has a nonzero.
// Unflagged rows are exact zeros and their memory is never read.
__global__ __launch_bounds__(256, 4) void convt_kernel(
    const float* __restrict__ in, float* __restrict__ out,
    const unsigned* __restrict__ Fprev, unsigned* __restrict__ Fout,
    const unsigned* __restrict__ cntPrev, unsigned* __restrict__ cntOut,
    const unsigned* __restrict__ pmin, const unsigned* __restrict__ pmax,
    unsigned* __restrict__ omin, unsigned* __restrict__ omax,
    double* __restrict__ osum) {
    if (*cntPrev == 0u) return;  // field died: absorbing state

    int blk = blockIdx.x;
    blk = (blk & 7) * (NTILES >> 3) + (blk >> 3);
    const int s = blk >> 6, ty = blk & 63, ry = ty << 4;
    const int tid = threadIdx.x, lane = tid & 63, w = tid >> 6;
    const int xb = lane << 4;
    const size_t sbase = (size_t)s * NPIX;

    // M: bit (i+1) = row ry+i flagged, i in [-1,16]
    const unsigned* Fs = Fprev + s * FWPS;
    const int w32 = ty >> 1, sh = (ty & 1) * 16;
    const unsigned cur = Fs[w32];
    unsigned M = ((cur >> sh) & 0xFFFFu) << 1;
    if (ty > 0)
        M |= (ty & 1) ? ((cur >> 15) & 1u) : ((Fs[w32 - 1] >> 31) & 1u);
    if (ty < TPS - 1) {
        const unsigned nb = (ty & 1) ? (Fs[w32 + 1] & 1u) : ((cur >> 16) & 1u);
        M |= nb << 17;
    }
    if (M == 0u) {  // nothing in reach: tile output exactly zero
        if (tid == 0) atomicMin(&omin[s], 0u);
        return;
    }

    float a = 1.f, cc = 0.f;
    {
        const float mn = __uint_as_float(pmin[s]);
        const float mx = __uint_as_float(pmax[s]);
        const float ptp = mx - mn;
        if (ptp > 0.f) { a = 1.f / ptp; cc = mn; }
    }

    const int r0 = w << 2;
    float A[16], B[16], C[16], O[16];

    auto loadRow = [&](int y, float* V) {
        const bool ok =
            (y >= 0 && y < HH) && (((M >> (y - ry + 1)) & 1u) != 0u);
        if (!ok) {
#pragma unroll
            for (int j = 0; j < 16; ++j) V[j] = 0.f;
            return;
        }
        const size_t idx = sbase + (size_t)y * WW + xb;
#pragma unroll
        for (int q = 0; q < 4; ++q) {
            const float4 v = ld4f(in + idx + 4 * q);
            V[4 * q + 0] = v.x;
            V[4 * q + 1] = v.y;
            V[4 * q + 2] = v.z;
            V[4 * q + 3] = v.w;
        }
    };

    loadRow(ry + r0 - 1, A);
    loadRow(ry + r0, B);

    float lmin = 3.4e38f, lmax = 0.f, lsum = 0.f;
    unsigned rowbits = 0u;

#pragma unroll
    for (int r = 0; r < 4; ++r) {
        const int y = ry + r0 + r;
        loadRow(y + 1, C);
        const bool act = (((M >> (r0 + r)) & 7u) != 0u);
        if (act) {
            float lfe = __shfl_up(B[15], 1);
            if (lane == 0) lfe = 0.f;
            float rte = __shfl_down(B[0], 1);
            if (lane == 63) rte = 0.f;
            const float vert =
                1.f + (y > 0 ? 1.f : 0.f) + (y < HH - 1 ? 1.f : 0.f);
            bool nz = false;
#pragma unroll
            for (int j = 0; j < 16; ++j) {
                const float lf = (j == 0) ? lfe : B[j - 1];
                const float rt = (j == 15) ? rte : B[j + 1];
                const float conv = 0.2f * (A[j] + C[j] + B[j] + lf + rt);
                const int x = xb + j;
                const float kf = 0.2f * (vert + (x > 0 ? 1.f : 0.f) +
                                         (x < WW - 1 ? 1.f : 0.f));
                const float dil = (conv - cc * kf) * a;
                const float er = fmaxf(dil - 0.5f, 0.f);
                O[j] = er;
                lmin = fminf(lmin, er);
                lmax = fmaxf(lmax, er);
                lsum += er;
                nz = nz || (er > 0.f);
            }
            if (__ballot(nz) != 0ull) {
                const size_t oidx = sbase + (size_t)y * WW + xb;
#pragma unroll
                for (int q = 0; q < 4; ++q)
                    *reinterpret_cast<float4*>(out + oidx + 4 * q) =
                        make_float4(O[4 * q], O[4 * q + 1], O[4 * q + 2],
                                    O[4 * q + 3]);
                rowbits |= 1u << (r0 + r);
            }
        } else {
            lmin = fminf(lmin, 0.f);
        }
#pragma unroll
        for (int j = 0; j < 16; ++j) {
            A[j] = B[j];
            B[j] = C[j];
        }
    }

#pragma unroll
    for (int off = 32; off > 0; off >>= 1) {
        lmin = fminf(lmin, __shfl_down(lmin, off));
        lmax = fmaxf(lmax, __shfl_down(lmax, off));
        lsum += __shfl_down(lsum, off);
    }
    __shared__ float smn[4], smx[4], ssm[4];
    __shared__ unsigned sfb[4];
    if (lane == 0) {
        smn[w] = lmin;
        smx[w] = lmax;
        ssm[w] = lsum;
        sfb[w] = rowbits;
    }
    __syncthreads();
    if (tid == 0) {
        const unsigned fmask = sfb[0] | sfb[1] | sfb[2] | sfb[3];
        float bmn = smn[0], bmx = smx[0], bsm = ssm[0];
#pragma unroll
        for (int i = 1; i < 4; ++i) {
            bmn = fminf(bmn, smn[i]);
            bmx = fmaxf(bmx, smx[i]);
            bsm += ssm[i];
        }
        if (fmask) {
            atomicOr(&Fout[s * FWPS + w32], fmask << sh);
            atomicAdd(cntOut, 1u);
        }
        atomicMin(&omin[s], __float_as_uint(bmn));
        if (bmx > 0.f) atomicMax(&omax[s], __float_as_uint(bmx));
        if (bsm > 0.f) atomicAdd(&osum[s], (double)bsm);
    }
}

__global__ void init_kernel(unsigned* __restrict__ minb,
                            unsigned* __restrict__ maxb,
                            double* __restrict__ sums,
                            unsigned* __restrict__ F,
                            unsigned* __restrict__ cnt) {
    const int i = blockIdx.x * blockDim.x + threadIdx.x;
    if (i < NEROS * BATCH) {
        minb[i] = 0x7f800000u;  // +inf
        maxb[i] = 0u;
        sums[i] = 0.0;
    }
    if (i < NEROS * BATCH * FWPS) F[i] = 0u;
    if (i < NEROS) cnt[i] = 0u;
}

__global__ void final_kernel(const unsigned* __restrict__ minb,
                             const unsigned* __restrict__ maxb,
                             const double* __restrict__ sums,
                             float* __restrict__ out) {
    const int s = threadIdx.x;
    double tot = 0.0;
    if (s < BATCH) {
        for (int k = 0; k < NEROS; ++k) {
            const float mn = __uint_as_float(minb[k * BATCH + s]);
            const float mx = __uint_as_float(maxb[k * BATCH + s]);
            const double sm = sums[k * BATCH + s];
            const float ptp = mx - mn;
            double v;
            if (ptp > 0.f)
                v = (sm - (double)NPIX * (double)mn) / (double)ptp;
            else
                v = sm;
            tot += (double)((k + 1) * (k + 1)) * v;
        }
    }
#pragma unroll
    for (int off = 32; off > 0; off >>= 1) tot += __shfl_down(tot, off);
    if (s == 0) out[0] = (float)(tot / ((double)BATCH * (double)NPIX));
}

extern "C" void kernel_launch(void* const* d_in, const int* in_sizes, int n_in,
                              void* d_out, int out_size, void* d_ws,
                              size_t ws_size, hipStream_t stream) {
    const float* pred = (const float*)d_in[0];
    const float* tgt = (const float*)d_in[1];
    float* out = (float*)d_out;

    float* buf0 = (float*)d_ws;
    float* buf1 = buf0 + (size_t)BATCH * NPIX;
    unsigned* minb = (unsigned*)(buf1 + (size_t)BATCH * NPIX);
    unsigned* maxb = minb + NEROS * BATCH;
    double* sums = (double*)(maxb + NEROS * BATCH);
    unsigned* F = (unsigned*)(sums + NEROS * BATCH);
    unsigned* cnt = F + (size_t)NEROS * BATCH * FWPS;

    init_kernel<<<40, 256, 0, stream>>>(minb, maxb, sums, F, cnt);

    conv0_kernel<<<NTILES, 512, 0, stream>>>(pred, tgt, buf0, F, &cnt[0], minb,
                                             maxb, sums);

    float* bufs[2] = {buf0, buf1};
    for (int k = 1; k < NEROS; ++k) {
        const float* src = bufs[(k - 1) & 1];
        float* dst = bufs[k & 1];
        convt_kernel<<<NTILES, 256, 0, stream>>>(
            src, dst, F + (size_t)(k - 1) * BATCH * FWPS,
            F + (size_t)k * BATCH * FWPS, &cnt[k - 1], &cnt[k],
            minb + (size_t)(k - 1) * BATCH, maxb + (size_t)(k - 1) * BATCH,
            minb + (size_t)k * BATCH, maxb + (size_t)k * BATCH,
            sums + (size_t)k * BATCH);
    }

    final_kernel<<<1, 64, 0, stream>>>(minb, maxb, sums, out);
}